// Round 1
// baseline (671.182 us; speedup 1.0000x reference)
//
#include <hip/hip_runtime.h>
#include <hip/hip_bf16.h>
#include <math.h>

#define BIGNEG (-1000000000.0f)

// Problem-fixed sizes: b=4, N1=512, d=64, C1=32, K=32, C=33, N=513
// ws float offsets
constexpr int OFF_MINV   = 0;        // 64*64 = 4096
constexpr int OFF_LOGDET = 4096;     // 1
constexpr int OFF_Q      = 4100;     // 32*64 = 2048   q[c][t] = Minv @ mean_c
constexpr int OFF_S      = 6148;     // 32             s[c] = mean_c . q[c]
constexpr int OFF_TRANS  = 6180;     // 33*33 = 1089
constexpr int OFF_LENAUG = 7269;     // 32*33 = 1056
constexpr int OFF_INITA  = 8325;     // 33
constexpr int OFF_EOS    = 8358;     // 513
constexpr int OFF_EMLAST = 8871;     // 33
constexpr int OFF_EM     = 8904;     // 4*512*32 = 65536
constexpr int OFF_CSUM   = 74440;    // 4*514*33 = 67848 ; end = 142288 floats (~569 KB)

__global__ __launch_bounds__(256) void setup_kernel(
    const float* __restrict__ cov, const float* __restrict__ means,
    const float* __restrict__ plr, const float* __restrict__ tlogits,
    const float* __restrict__ ilogits, const int* __restrict__ lengths,
    float* __restrict__ ws)
{
    __shared__ float Lm[64][65];
    __shared__ float Y[64][65];
    __shared__ float lse_t[32];
    __shared__ float ilse;
    const int tid = threadIdx.x;

    for (int idx = tid; idx < 64 * 64; idx += 256) Lm[idx >> 6][idx & 63] = cov[idx];
    __syncthreads();

    // Cholesky (lower), column by column
    for (int j = 0; j < 64; ++j) {
        if (tid == 0) {
            float s = Lm[j][j];
            for (int m = 0; m < j; ++m) s -= Lm[j][m] * Lm[j][m];
            Lm[j][j] = sqrtf(s);
        }
        __syncthreads();
        const float dia = Lm[j][j];
        if (tid > j && tid < 64) {
            float s = Lm[tid][j];
            for (int m = 0; m < j; ++m) s -= Lm[tid][m] * Lm[j][m];
            Lm[tid][j] = s / dia;
        }
        __syncthreads();
    }
    if (tid == 0) {
        float ld = 0.f;
        for (int j = 0; j < 64; ++j) ld += logf(Lm[j][j]);
        ws[OFF_LOGDET] = 2.f * ld;
    }
    // Minv: thread i solves L y = e_i then L^T x = y (in place)
    if (tid < 64) {
        const int i = tid;
        for (int k = 0; k < 64; ++k) {
            if (k < i) { Y[k][i] = 0.f; continue; }
            float v = (k == i) ? 1.f : 0.f;
            for (int m = i; m < k; ++m) v -= Lm[k][m] * Y[m][i];
            Y[k][i] = v / Lm[k][k];
        }
        for (int k = 63; k >= 0; --k) {
            float v = Y[k][i];
            for (int m = k + 1; m < 64; ++m) v -= Lm[m][k] * Y[m][i];
            Y[k][i] = v / Lm[k][k];
        }
    }
    __syncthreads();
    for (int idx = tid; idx < 4096; idx += 256) ws[OFF_MINV + idx] = Y[idx >> 6][idx & 63];
    // q[c][t] = sum_e Minv[t][e] * means[c][e]
    for (int idx = tid; idx < 32 * 64; idx += 256) {
        const int c = idx >> 6, t = idx & 63;
        float acc = 0.f;
        for (int e = 0; e < 64; ++e) acc += Y[t][e] * means[c * 64 + e];
        ws[OFF_Q + c * 64 + t] = acc;
    }
    __syncthreads();
    if (tid < 32) {
        const int c = tid;
        float acc = 0.f;
        for (int t = 0; t < 64; ++t) acc += means[c * 64 + t] * ws[OFF_Q + c * 64 + t];
        ws[OFF_S + c] = acc;
    }
    // column-wise logsumexp of masked transition logits
    if (tid < 32) {
        const int j = tid;
        float mx = -INFINITY;
        for (int i = 0; i < 32; ++i) {
            const float x = (i == j) ? BIGNEG : tlogits[i * 32 + j];
            mx = fmaxf(mx, x);
        }
        float sum = 0.f;
        for (int i = 0; i < 32; ++i) {
            const float x = (i == j) ? BIGNEG : tlogits[i * 32 + j];
            sum += expf(x - mx);
        }
        lse_t[j] = mx + logf(sum);
    }
    if (tid == 0) {
        float mx = -INFINITY;
        for (int i = 0; i < 32; ++i) mx = fmaxf(mx, ilogits[i]);
        float sum = 0.f;
        for (int i = 0; i < 32; ++i) sum += expf(ilogits[i] - mx);
        ilse = mx + logf(sum);
    }
    __syncthreads();
    // trans_aug (33x33): [:32,:32]=trans (diag masked), row 32 = 0, col 32 (rows<32) = BIGNEG
    for (int idx = tid; idx < 1089; idx += 256) {
        const int i = idx / 33, j = idx - i * 33;
        float v;
        if (i == 32) v = 0.f;
        else if (j == 32) v = BIGNEG;
        else if (i == j) v = BIGNEG - lse_t[j];
        else v = tlogits[i * 32 + j] - lse_t[j];
        ws[OFF_TRANS + idx] = v;
    }
    if (tid < 33) ws[OFF_INITA + tid] = (tid < 32) ? (ilogits[tid] - ilse) : BIGNEG;
    // len_aug (32x33)
    for (int idx = tid; idx < 32 * 33; idx += 256) {
        const int k = idx / 33, j = idx - k * 33;
        float v;
        if (j < 32) v = (float)k * plr[j] - expf(plr[j]) - lgammaf((float)k + 1.f);
        else        v = (k == 1) ? 0.f : BIGNEG;
        ws[OFF_LENAUG + idx] = v;
    }
    // eos column (shared across batch, per reference's any() over batches)
    for (int t = tid; t < 513; t += 256) {
        bool any = false;
        for (int b2 = 0; b2 < 4; ++b2) any |= (lengths[b2] == t);
        ws[OFF_EOS + t] = any ? 0.f : BIGNEG;
    }
    // em_last[i] = em_aug[:, 512, i]  (batch-independent)
    if (tid < 33) {
        float v = BIGNEG;
        if (tid == 32) {
            bool any = false;
            for (int b2 = 0; b2 < 4; ++b2) any |= (lengths[b2] == 512);
            v = any ? 0.f : BIGNEG;
        }
        ws[OFF_EMLAST + tid] = v;
    }
}

// em[b,n,c] = -0.5*(f'Minv f - 2 f'q_c + s_c + d*log(2pi) + logdet); one wave per (b,n)
__global__ __launch_bounds__(256) void em_kernel(
    const float* __restrict__ features, float* __restrict__ ws)
{
    __shared__ float sM[64][65];
    __shared__ float sq[32][65];
    __shared__ float sf[4][64];
    __shared__ float ss[32];
    const int tid = threadIdx.x;
    for (int idx = tid; idx < 4096; idx += 256) sM[idx >> 6][idx & 63] = ws[OFF_MINV + idx];
    for (int idx = tid; idx < 2048; idx += 256) sq[idx >> 6][idx & 63] = ws[OFF_Q + idx];
    if (tid < 32) ss[tid] = ws[OFF_S + tid];
    const float logdet = ws[OFF_LOGDET];
    const int w = tid >> 6, lane = tid & 63;
    const int p = blockIdx.x * 4 + w;       // (b,n) pair index, b = p>>9, n = p&511
    sf[w][lane] = features[p * 64 + lane];
    __syncthreads();

    float u = 0.f;
    for (int e = 0; e < 64; ++e) u += sM[lane][e] * sf[w][e];
    float a = sf[w][lane] * u;
    for (int m = 32; m >= 1; m >>= 1) a += __shfl_xor(a, m, 64);

    const int c = lane >> 1, h = lane & 1;
    float pd = 0.f;
    const int eb = h * 32;
    for (int e = 0; e < 32; ++e) pd += sf[w][eb + e] * sq[c][eb + e];
    pd += __shfl_xor(pd, 1, 64);

    const float em = -0.5f * (a - 2.f * pd + ss[c] + 64.f * 1.8378770664093453f + logdet);
    if (h == 0) ws[OFF_EM + p * 32 + c] = em;
}

// prefix sums over masked em_aug: csum[b][0..513][c]
__global__ __launch_bounds__(160) void csum_kernel(
    const int* __restrict__ lengths, float* __restrict__ ws)
{
    const int id = threadIdx.x;
    if (id >= 132) return;
    const int b = id / 33, c = id - b * 33;
    const int len = lengths[b];
    float* cs = ws + OFF_CSUM + b * 514 * 33 + c;
    const float* emp = ws + OFF_EM + b * 512 * 32 + c;
    const float* eos = ws + OFF_EOS;
    float acc = 0.f;
    cs[0] = 0.f;
    for (int t = 0; t < 513; ++t) {
        float v;
        if (c < 32) v = (t < 512 && t < len) ? emp[t * 32] : BIGNEG;
        else        v = eos[t];
        acc += v;
        cs[(t + 1) * 33] = acc;
    }
}

// scores[b,t,k,i,j] = trans[i,j] + len_aug[k,j] + wins[b,t,k,j] + t0*init[j] + last*em_last[i]
__global__ __launch_bounds__(256) void score_kernel(
    const float* __restrict__ ws, float* __restrict__ out)
{
    __shared__ float sT[1089];
    __shared__ float sA[32 * 33];
    const int tid = threadIdx.x;
    const int blk = blockIdx.x;
    const int b = blk >> 9, t = blk & 511;
    const float* trans  = ws + OFF_TRANS;
    const float* lenaug = ws + OFF_LENAUG;
    const float* inita  = ws + OFF_INITA;
    const float* emlast = ws + OFF_EMLAST;
    const float* cs     = ws + OFF_CSUM + b * 514 * 33;

    for (int idx = tid; idx < 1089; idx += 256) sT[idx] = trans[idx];
    for (int idx = tid; idx < 1056; idx += 256) {
        const int k = idx / 33, j = idx - k * 33;
        int end = t + k; if (end > 513) end = 513;
        float v = cs[end * 33 + j] - cs[t * 33 + j] + lenaug[idx];
        if (t == 0) v += inita[j];
        sA[idx] = v;
    }
    __syncthreads();

    float tv[5], el[5];
    int jj[5];
#pragma unroll
    for (int m = 0; m < 5; ++m) {
        const int idx = tid + 256 * m;
        if (idx < 1089) {
            const int i = idx / 33;
            jj[m] = idx - i * 33;
            tv[m] = sT[idx];
            el[m] = emlast[i];
        } else { jj[m] = 0; tv[m] = 0.f; el[m] = 0.f; }
    }
    const bool has5 = (tid < 65);
    const int kk = 512 - t;   // the unique k>=1 receiving em_last (if < 32)
    float* ob = out + (size_t)(b * 512 + t) * 32 * 1089;
    for (int k = 0; k < 32; ++k) {
        const float add = (k == kk) ? 1.f : 0.f;
        const float* Ak = sA + k * 33;
        float* op = ob + (size_t)k * 1089;
#pragma unroll
        for (int m = 0; m < 4; ++m)
            op[tid + 256 * m] = tv[m] + Ak[jj[m]] + add * el[m];
        if (has5)
            op[tid + 1024] = tv[4] + Ak[jj[4]] + add * el[4];
    }
}

extern "C" void kernel_launch(void* const* d_in, const int* in_sizes, int n_in,
                              void* d_out, int out_size, void* d_ws, size_t ws_size,
                              hipStream_t stream) {
    (void)in_sizes; (void)n_in; (void)out_size; (void)ws_size;
    const float* features = (const float*)d_in[0];   // (4,512,64)
    const int*   lengths  = (const int*)d_in[1];     // (4,)
    const float* means    = (const float*)d_in[2];   // (32,64)
    const float* cov      = (const float*)d_in[3];   // (64,64)
    const float* plr      = (const float*)d_in[4];   // (32,)
    const float* tlog     = (const float*)d_in[5];   // (32,32)
    const float* ilog     = (const float*)d_in[6];   // (32,)
    float* ws  = (float*)d_ws;
    float* out = (float*)d_out;

    setup_kernel<<<1, 256, 0, stream>>>(cov, means, plr, tlog, ilog, lengths, ws);
    em_kernel<<<512, 256, 0, stream>>>(features, ws);
    csum_kernel<<<1, 160, 0, stream>>>(lengths, ws);
    score_kernel<<<2048, 256, 0, stream>>>(ws, out);
}

// Round 2
// 474.657 us; speedup vs baseline: 1.4140x; 1.4140x over previous
//
#include <hip/hip_runtime.h>
#include <hip/hip_bf16.h>
#include <math.h>

#define BIGNEG (-1000000000.0f)

// Problem-fixed sizes: b=4, N1=512, d=64, C1=32, K=32, C=33, N=513
// ws float offsets
constexpr int OFF_MINV   = 0;        // 64*64 = 4096
constexpr int OFF_LOGDET = 4096;     // 1
constexpr int OFF_Q      = 4100;     // 32*64 = 2048   q[c][t] = Minv @ mean_c
constexpr int OFF_S      = 6148;     // 32             s[c] = mean_c . q[c]
constexpr int OFF_TRANS  = 6180;     // 33*33 = 1089
constexpr int OFF_LENAUG = 7269;     // 32*33 = 1056
constexpr int OFF_INITA  = 8325;     // 33
constexpr int OFF_EOS    = 8358;     // 513
constexpr int OFF_EMLAST = 8871;     // 33
constexpr int OFF_EMT    = 8904;     // 4*32*512 = 65536  (em transposed: [b][c][t])
constexpr int OFF_CSUM   = 74440;    // 4*514*33 = 67848 ; end = 142288 floats (~569 KB)

__global__ __launch_bounds__(256) void setup_kernel(
    const float* __restrict__ cov, const float* __restrict__ means,
    const float* __restrict__ plr, const float* __restrict__ tlogits,
    const float* __restrict__ ilogits, const int* __restrict__ lengths,
    float* __restrict__ ws)
{
    // A[r][0..63] = cov, A[r][64..127] = identity -> becomes inverse
    __shared__ float A[64][130];
    __shared__ float piv_s;
    __shared__ float lse_t[32];
    __shared__ float ilse;
    const int tid = threadIdx.x;

    for (int idx = tid; idx < 64 * 64; idx += 256) {
        const int r = idx >> 6, c = idx & 63;
        A[r][c] = cov[idx];
        A[r][64 + c] = (r == c) ? 1.f : 0.f;
    }
    __syncthreads();

    // Gauss-Jordan, parallel: 64 rows x 4 threads/row, 32 cols each
    float ld = 0.f;                      // only meaningful on tid 0
    const int r = tid >> 2;
    const int c0 = (tid & 3) << 5;
    for (int p = 0; p < 64; ++p) {
        if (tid == 0) {
            const float pv = A[p][p];
            ld += logf(pv);
            piv_s = 1.f / pv;
        }
        __syncthreads();
        if (tid < 128) A[p][tid] *= piv_s;
        __syncthreads();
        const float f = (r != p) ? A[r][p] : 0.f;
        // all 4 quarter-threads of a row are in the same wave -> the f reads
        // retire (lockstep) before any of this wave's stores to A[r][p]
        #pragma unroll 8
        for (int c = c0; c < c0 + 32; ++c) A[r][c] -= f * A[p][c];
        __syncthreads();
    }
    if (tid == 0) ws[OFF_LOGDET] = ld;

    for (int idx = tid; idx < 4096; idx += 256)
        ws[OFF_MINV + idx] = A[idx >> 6][64 + (idx & 63)];
    // q[c][t] = sum_e Minv[t][e] * means[c][e]
    for (int idx = tid; idx < 32 * 64; idx += 256) {
        const int c = idx >> 6, t = idx & 63;
        float acc = 0.f;
        for (int e = 0; e < 64; ++e) acc += A[t][64 + e] * means[c * 64 + e];
        ws[OFF_Q + c * 64 + t] = acc;
    }
    __syncthreads();
    if (tid < 32) {
        const int c = tid;
        float acc = 0.f;
        for (int t = 0; t < 64; ++t) acc += means[c * 64 + t] * ws[OFF_Q + c * 64 + t];
        ws[OFF_S + c] = acc;
    }
    // column-wise logsumexp of masked transition logits
    if (tid < 32) {
        const int j = tid;
        float mx = -INFINITY;
        for (int i = 0; i < 32; ++i) {
            const float x = (i == j) ? BIGNEG : tlogits[i * 32 + j];
            mx = fmaxf(mx, x);
        }
        float sum = 0.f;
        for (int i = 0; i < 32; ++i) {
            const float x = (i == j) ? BIGNEG : tlogits[i * 32 + j];
            sum += expf(x - mx);
        }
        lse_t[j] = mx + logf(sum);
    }
    if (tid == 0) {
        float mx = -INFINITY;
        for (int i = 0; i < 32; ++i) mx = fmaxf(mx, ilogits[i]);
        float sum = 0.f;
        for (int i = 0; i < 32; ++i) sum += expf(ilogits[i] - mx);
        ilse = mx + logf(sum);
    }
    __syncthreads();
    // trans_aug (33x33): [:32,:32]=trans (diag masked), row 32 = 0, col 32 (rows<32) = BIGNEG
    for (int idx = tid; idx < 1089; idx += 256) {
        const int i = idx / 33, j = idx - i * 33;
        float v;
        if (i == 32) v = 0.f;
        else if (j == 32) v = BIGNEG;
        else if (i == j) v = BIGNEG - lse_t[j];
        else v = tlogits[i * 32 + j] - lse_t[j];
        ws[OFF_TRANS + idx] = v;
    }
    if (tid < 33) ws[OFF_INITA + tid] = (tid < 32) ? (ilogits[tid] - ilse) : BIGNEG;
    // len_aug (32x33)
    for (int idx = tid; idx < 32 * 33; idx += 256) {
        const int k = idx / 33, j = idx - k * 33;
        float v;
        if (j < 32) v = (float)k * plr[j] - expf(plr[j]) - lgammaf((float)k + 1.f);
        else        v = (k == 1) ? 0.f : BIGNEG;
        ws[OFF_LENAUG + idx] = v;
    }
    // eos column (shared across batch, per reference's any() over batches)
    for (int t = tid; t < 513; t += 256) {
        bool any = false;
        for (int b2 = 0; b2 < 4; ++b2) any |= (lengths[b2] == t);
        ws[OFF_EOS + t] = any ? 0.f : BIGNEG;
    }
    // em_last[i] = em_aug[:, 512, i]  (batch-independent)
    if (tid < 33) {
        float v = BIGNEG;
        if (tid == 32) {
            bool any = false;
            for (int b2 = 0; b2 < 4; ++b2) any |= (lengths[b2] == 512);
            v = any ? 0.f : BIGNEG;
        }
        ws[OFF_EMLAST + tid] = v;
    }
}

// em_t[b][c][n] = -0.5*(f'Minv f - 2 f'q_c + s_c + d*log(2pi) + logdet); one wave per (b,n)
__global__ __launch_bounds__(256) void em_kernel(
    const float* __restrict__ features, float* __restrict__ ws)
{
    __shared__ float sM[64][65];
    __shared__ float sq[32][65];
    __shared__ float sf[4][64];
    __shared__ float ss[32];
    const int tid = threadIdx.x;
    for (int idx = tid; idx < 4096; idx += 256) sM[idx >> 6][idx & 63] = ws[OFF_MINV + idx];
    for (int idx = tid; idx < 2048; idx += 256) sq[idx >> 6][idx & 63] = ws[OFF_Q + idx];
    if (tid < 32) ss[tid] = ws[OFF_S + tid];
    const float logdet = ws[OFF_LOGDET];
    const int w = tid >> 6, lane = tid & 63;
    const int p = blockIdx.x * 4 + w;       // (b,n) pair index, b = p>>9, n = p&511
    sf[w][lane] = features[p * 64 + lane];
    __syncthreads();

    float u = 0.f;
    for (int e = 0; e < 64; ++e) u += sM[lane][e] * sf[w][e];
    float a = sf[w][lane] * u;
    for (int m = 32; m >= 1; m >>= 1) a += __shfl_xor(a, m, 64);

    const int c = lane >> 1, h = lane & 1;
    float pd = 0.f;
    const int eb = h * 32;
    for (int e = 0; e < 32; ++e) pd += sf[w][eb + e] * sq[c][eb + e];
    pd += __shfl_xor(pd, 1, 64);

    const float em = -0.5f * (a - 2.f * pd + ss[c] + 64.f * 1.8378770664093453f + logdet);
    const int b = p >> 9, n = p & 511;
    if (h == 0) ws[OFF_EMT + (b * 32 + c) * 512 + n] = em;
}

// wave-parallel prefix sums: cs[b][0..513][c]. One 64-lane block per (b,c).
__global__ __launch_bounds__(64) void csum_kernel(
    const int* __restrict__ lengths, float* __restrict__ ws)
{
    const int blk = blockIdx.x;
    const int b = blk / 33, c = blk - b * 33;
    const int lane = threadIdx.x;
    const int len = lengths[b];
    const float* emt = ws + OFF_EMT + (b * 32 + c) * 512;
    const float* eos = ws + OFF_EOS;
    const int t0 = lane * 9;            // lanes 0..56 cover t in [0,513)
    float v[9];
#pragma unroll
    for (int i = 0; i < 9; ++i) {
        const int t = t0 + i;
        float x = 0.f;
        if (t <= 512) {
            if (c == 32)      x = eos[t];
            else if (t < 512 && t < len) x = emt[t];
            else              x = BIGNEG;
        }
        v[i] = x;
    }
#pragma unroll
    for (int i = 1; i < 9; ++i) v[i] += v[i - 1];
    const float tot = v[8];
    float inc = tot;
    for (int off = 1; off < 64; off <<= 1) {
        const float y = __shfl_up(inc, off, 64);
        if (lane >= off) inc += y;
    }
    const float excl = inc - tot;
    float* cs = ws + OFF_CSUM + b * 514 * 33 + c;
    if (lane == 0) cs[0] = 0.f;
#pragma unroll
    for (int i = 0; i < 9; ++i) {
        const int t = t0 + i;
        if (t <= 512) cs[(t + 1) * 33] = excl + v[i];
    }
}

// scores[b,t,k,i,j] = trans[i,j] + len_aug[k,j] + wins[b,t,k,j] + t0*init[j] + last*em_last[i]
__global__ __launch_bounds__(256) void score_kernel(
    const float* __restrict__ ws, float* __restrict__ out)
{
    __shared__ float sT[1089];
    __shared__ float sA[32 * 33];
    const int tid = threadIdx.x;
    const int blk = blockIdx.x;
    const int b = blk >> 9, t = blk & 511;
    const float* trans  = ws + OFF_TRANS;
    const float* lenaug = ws + OFF_LENAUG;
    const float* inita  = ws + OFF_INITA;
    const float* emlast = ws + OFF_EMLAST;
    const float* cs     = ws + OFF_CSUM + b * 514 * 33;

    for (int idx = tid; idx < 1089; idx += 256) sT[idx] = trans[idx];
    for (int idx = tid; idx < 1056; idx += 256) {
        const int k = idx / 33, j = idx - k * 33;
        int end = t + k; if (end > 513) end = 513;
        float v = cs[end * 33 + j] - cs[t * 33 + j] + lenaug[idx];
        if (t == 0) v += inita[j];
        sA[idx] = v;
    }
    __syncthreads();

    float tv[5], el[5];
    int jj[5];
#pragma unroll
    for (int m = 0; m < 5; ++m) {
        const int idx = tid + 256 * m;
        if (idx < 1089) {
            const int i = idx / 33;
            jj[m] = idx - i * 33;
            tv[m] = sT[idx];
            el[m] = emlast[i];
        } else { jj[m] = 0; tv[m] = 0.f; el[m] = 0.f; }
    }
    const bool has5 = (tid < 65);
    const int kk = 512 - t;   // the unique k>=1 receiving em_last (if < 32)
    float* ob = out + (size_t)(b * 512 + t) * 32 * 1089;
    for (int k = 0; k < 32; ++k) {
        const float add = (k == kk) ? 1.f : 0.f;
        const float* Ak = sA + k * 33;
        float* op = ob + (size_t)k * 1089;
#pragma unroll
        for (int m = 0; m < 4; ++m)
            op[tid + 256 * m] = tv[m] + Ak[jj[m]] + add * el[m];
        if (has5)
            op[tid + 1024] = tv[4] + Ak[jj[4]] + add * el[4];
    }
}

extern "C" void kernel_launch(void* const* d_in, const int* in_sizes, int n_in,
                              void* d_out, int out_size, void* d_ws, size_t ws_size,
                              hipStream_t stream) {
    (void)in_sizes; (void)n_in; (void)out_size; (void)ws_size;
    const float* features = (const float*)d_in[0];   // (4,512,64)
    const int*   lengths  = (const int*)d_in[1];     // (4,)
    const float* means    = (const float*)d_in[2];   // (32,64)
    const float* cov      = (const float*)d_in[3];   // (64,64)
    const float* plr      = (const float*)d_in[4];   // (32,)
    const float* tlog     = (const float*)d_in[5];   // (32,32)
    const float* ilog     = (const float*)d_in[6];   // (32,)
    float* ws  = (float*)d_ws;
    float* out = (float*)d_out;

    setup_kernel<<<1, 256, 0, stream>>>(cov, means, plr, tlog, ilog, lengths, ws);
    em_kernel<<<512, 256, 0, stream>>>(features, ws);
    csum_kernel<<<132, 64, 0, stream>>>(lengths, ws);
    score_kernel<<<2048, 256, 0, stream>>>(ws, out);
}

// Round 3
// 473.709 us; speedup vs baseline: 1.4169x; 1.0020x over previous
//
#include <hip/hip_runtime.h>
#include <hip/hip_bf16.h>
#include <math.h>

#define BIGNEG (-1000000000.0f)

// Problem-fixed sizes: b=4, N1=512, d=64, C1=32, K=32, C=33, N=513
// ws float offsets
constexpr int OFF_MINV   = 0;        // 64*64 = 4096
constexpr int OFF_LOGDET = 4096;     // 1
constexpr int OFF_Q      = 4100;     // 32*64 = 2048   q[c][t] = Minv @ mean_c
constexpr int OFF_S      = 6148;     // 32             s[c] = mean_c . q[c]
constexpr int OFF_TRANS  = 6180;     // 33*33 = 1089
constexpr int OFF_LENAUG = 7269;     // 32*33 = 1056
constexpr int OFF_INITA  = 8325;     // 33
constexpr int OFF_EOS    = 8358;     // 513
constexpr int OFF_EMLAST = 8871;     // 33
constexpr int OFF_EMT    = 8904;     // 4*32*512 = 65536  (em transposed: [b][c][t])
constexpr int OFF_CSUM   = 74440;    // 4*514*33 = 67848 ; end = 142288 floats (~569 KB)

__global__ __launch_bounds__(256) void setup_kernel(
    const float* __restrict__ cov, const float* __restrict__ means,
    const float* __restrict__ plr, const float* __restrict__ tlogits,
    const float* __restrict__ ilogits, const int* __restrict__ lengths,
    float* __restrict__ ws)
{
    // A[r][0..63] = cov, A[r][64..127] = identity.
    // Gauss-Jordan WITHOUT scaling the pivot row: after 64 pivots the left
    // half is diag(d_r) (each diagonal frozen after its own pivot step) and
    // the right half is diag(d_r) * cov^{-1}.  logdet = sum log d_r.
    __shared__ float A[64][130];
    __shared__ float rd[64];     // 1/d_r
    __shared__ float lg[64];     // log d_r
    __shared__ float lse_t[32];
    __shared__ float ilse;
    const int tid = threadIdx.x;

    for (int idx = tid; idx < 64 * 64; idx += 256) {
        const int r = idx >> 6, c = idx & 63;
        A[r][c] = cov[idx];
        A[r][64 + c] = (r == c) ? 1.f : 0.f;
    }
    __syncthreads();

    // 64 rows x 4 threads/row; thread g of a row owns cols c == g (mod 4).
    // One barrier per pivot: row r's f-read and its own writes are ordered
    // because a row's 4 threads live in the same wave; no thread writes any
    // row it doesn't own (row p's writes are value-preserving: f==0).
    const int r = tid >> 2;
    const int g = tid & 3;
    for (int p = 0; p < 64; ++p) {
        const float d = A[p][p];
        const float f = (r == p) ? 0.f : A[r][p] / d;
        #pragma unroll
        for (int i = 0; i < 32; ++i) {
            const int c = g + (i << 2);
            A[r][c] = fmaf(-f, A[p][c], A[r][c]);
        }
        __syncthreads();
    }
    if (tid < 64) {
        const float d = A[tid][tid];
        rd[tid] = 1.f / d;
        lg[tid] = logf(d);
    }
    __syncthreads();
    if (tid == 0) {
        float ld = 0.f;
        for (int j = 0; j < 64; ++j) ld += lg[j];
        ws[OFF_LOGDET] = ld;
    }

    for (int idx = tid; idx < 4096; idx += 256) {
        const int row = idx >> 6;
        ws[OFF_MINV + idx] = A[row][64 + (idx & 63)] * rd[row];
    }
    // q[c][t] = sum_e Minv[t][e] * means[c][e]
    for (int idx = tid; idx < 32 * 64; idx += 256) {
        const int c = idx >> 6, t = idx & 63;
        float acc = 0.f;
        for (int e = 0; e < 64; ++e) acc += A[t][64 + e] * means[c * 64 + e];
        ws[OFF_Q + c * 64 + t] = acc * rd[t];
    }
    __syncthreads();
    if (tid < 32) {
        const int c = tid;
        float acc = 0.f;
        for (int t = 0; t < 64; ++t) acc += means[c * 64 + t] * ws[OFF_Q + c * 64 + t];
        ws[OFF_S + c] = acc;
    }
    // column-wise logsumexp of masked transition logits
    if (tid < 32) {
        const int j = tid;
        float mx = -INFINITY;
        for (int i = 0; i < 32; ++i) {
            const float x = (i == j) ? BIGNEG : tlogits[i * 32 + j];
            mx = fmaxf(mx, x);
        }
        float sum = 0.f;
        for (int i = 0; i < 32; ++i) {
            const float x = (i == j) ? BIGNEG : tlogits[i * 32 + j];
            sum += expf(x - mx);
        }
        lse_t[j] = mx + logf(sum);
    }
    if (tid == 0) {
        float mx = -INFINITY;
        for (int i = 0; i < 32; ++i) mx = fmaxf(mx, ilogits[i]);
        float sum = 0.f;
        for (int i = 0; i < 32; ++i) sum += expf(ilogits[i] - mx);
        ilse = mx + logf(sum);
    }
    __syncthreads();
    // trans_aug (33x33): [:32,:32]=trans (diag masked), row 32 = 0, col 32 (rows<32) = BIGNEG
    for (int idx = tid; idx < 1089; idx += 256) {
        const int i = idx / 33, j = idx - i * 33;
        float v;
        if (i == 32) v = 0.f;
        else if (j == 32) v = BIGNEG;
        else if (i == j) v = BIGNEG - lse_t[j];
        else v = tlogits[i * 32 + j] - lse_t[j];
        ws[OFF_TRANS + idx] = v;
    }
    if (tid < 33) ws[OFF_INITA + tid] = (tid < 32) ? (ilogits[tid] - ilse) : BIGNEG;
    // len_aug (32x33)
    for (int idx = tid; idx < 32 * 33; idx += 256) {
        const int k = idx / 33, j = idx - k * 33;
        float v;
        if (j < 32) v = (float)k * plr[j] - expf(plr[j]) - lgammaf((float)k + 1.f);
        else        v = (k == 1) ? 0.f : BIGNEG;
        ws[OFF_LENAUG + idx] = v;
    }
    // eos column (shared across batch, per reference's any() over batches)
    const int l0 = lengths[0], l1 = lengths[1], l2 = lengths[2], l3 = lengths[3];
    for (int t = tid; t < 513; t += 256) {
        const bool any = (l0 == t) | (l1 == t) | (l2 == t) | (l3 == t);
        ws[OFF_EOS + t] = any ? 0.f : BIGNEG;
    }
    // em_last[i] = em_aug[:, 512, i]  (batch-independent)
    if (tid < 33) {
        float v = BIGNEG;
        if (tid == 32) {
            const bool any = (l0 == 512) | (l1 == 512) | (l2 == 512) | (l3 == 512);
            v = any ? 0.f : BIGNEG;
        }
        ws[OFF_EMLAST + tid] = v;
    }
}

// em_t[b][c][n] = -0.5*(f'Minv f - 2 f'q_c + s_c + d*log(2pi) + logdet); one wave per (b,n)
__global__ __launch_bounds__(256) void em_kernel(
    const float* __restrict__ features, float* __restrict__ ws)
{
    __shared__ float sM[64][65];
    __shared__ float sq[32][65];
    __shared__ float sf[4][64];
    __shared__ float ss[32];
    const int tid = threadIdx.x;
    for (int idx = tid; idx < 4096; idx += 256) sM[idx >> 6][idx & 63] = ws[OFF_MINV + idx];
    for (int idx = tid; idx < 2048; idx += 256) sq[idx >> 6][idx & 63] = ws[OFF_Q + idx];
    if (tid < 32) ss[tid] = ws[OFF_S + tid];
    const float logdet = ws[OFF_LOGDET];
    const int w = tid >> 6, lane = tid & 63;
    const int p = blockIdx.x * 4 + w;       // (b,n) pair index, b = p>>9, n = p&511
    sf[w][lane] = features[p * 64 + lane];
    __syncthreads();

    float u = 0.f;
    for (int e = 0; e < 64; ++e) u += sM[lane][e] * sf[w][e];
    float a = sf[w][lane] * u;
    for (int m = 32; m >= 1; m >>= 1) a += __shfl_xor(a, m, 64);

    const int c = lane >> 1, h = lane & 1;
    float pd = 0.f;
    const int eb = h * 32;
    for (int e = 0; e < 32; ++e) pd += sf[w][eb + e] * sq[c][eb + e];
    pd += __shfl_xor(pd, 1, 64);

    const float em = -0.5f * (a - 2.f * pd + ss[c] + 64.f * 1.8378770664093453f + logdet);
    const int b = p >> 9, n = p & 511;
    if (h == 0) ws[OFF_EMT + (b * 32 + c) * 512 + n] = em;
}

// wave-parallel prefix sums: cs[b][0..513][c]. One 64-lane block per (b,c).
__global__ __launch_bounds__(64) void csum_kernel(
    const int* __restrict__ lengths, float* __restrict__ ws)
{
    const int blk = blockIdx.x;
    const int b = blk / 33, c = blk - b * 33;
    const int lane = threadIdx.x;
    const int len = lengths[b];
    const float* emt = ws + OFF_EMT + (b * 32 + c) * 512;
    const float* eos = ws + OFF_EOS;
    const int t0 = lane * 9;            // lanes 0..56 cover t in [0,513)
    float v[9];
#pragma unroll
    for (int i = 0; i < 9; ++i) {
        const int t = t0 + i;
        float x = 0.f;
        if (t <= 512) {
            if (c == 32)      x = eos[t];
            else if (t < 512 && t < len) x = emt[t];
            else              x = BIGNEG;
        }
        v[i] = x;
    }
#pragma unroll
    for (int i = 1; i < 9; ++i) v[i] += v[i - 1];
    const float tot = v[8];
    float inc = tot;
    for (int off = 1; off < 64; off <<= 1) {
        const float y = __shfl_up(inc, off, 64);
        if (lane >= off) inc += y;
    }
    const float excl = inc - tot;
    float* cs = ws + OFF_CSUM + b * 514 * 33 + c;
    if (lane == 0) cs[0] = 0.f;
#pragma unroll
    for (int i = 0; i < 9; ++i) {
        const int t = t0 + i;
        if (t <= 512) cs[(t + 1) * 33] = excl + v[i];
    }
}

// scores[b,t,k,i,j] = trans[i,j] + len_aug[k,j] + wins[b,t,k,j] + t0*init[j] + last*em_last[i]
__global__ __launch_bounds__(256) void score_kernel(
    const float* __restrict__ ws, float* __restrict__ out)
{
    __shared__ float sT[1089];
    __shared__ float sA[32 * 33];
    const int tid = threadIdx.x;
    const int blk = blockIdx.x;
    const int b = blk >> 9, t = blk & 511;
    const float* trans  = ws + OFF_TRANS;
    const float* lenaug = ws + OFF_LENAUG;
    const float* inita  = ws + OFF_INITA;
    const float* emlast = ws + OFF_EMLAST;
    const float* cs     = ws + OFF_CSUM + b * 514 * 33;

    for (int idx = tid; idx < 1089; idx += 256) sT[idx] = trans[idx];
    for (int idx = tid; idx < 1056; idx += 256) {
        const int k = idx / 33, j = idx - k * 33;
        int end = t + k; if (end > 513) end = 513;
        float v = cs[end * 33 + j] - cs[t * 33 + j] + lenaug[idx];
        if (t == 0) v += inita[j];
        sA[idx] = v;
    }
    __syncthreads();

    float tv[5], el[5];
    int jj[5];
#pragma unroll
    for (int m = 0; m < 5; ++m) {
        const int idx = tid + 256 * m;
        if (idx < 1089) {
            const int i = idx / 33;
            jj[m] = idx - i * 33;
            tv[m] = sT[idx];
            el[m] = emlast[i];
        } else { jj[m] = 0; tv[m] = 0.f; el[m] = 0.f; }
    }
    const bool has5 = (tid < 65);
    const int kk = 512 - t;   // the unique k>=1 receiving em_last (if < 32)
    float* ob = out + (size_t)(b * 512 + t) * 32 * 1089;
    for (int k = 0; k < 32; ++k) {
        const float add = (k == kk) ? 1.f : 0.f;
        const float* Ak = sA + k * 33;
        float* op = ob + (size_t)k * 1089;
#pragma unroll
        for (int m = 0; m < 4; ++m)
            __builtin_nontemporal_store(tv[m] + Ak[jj[m]] + add * el[m], op + tid + 256 * m);
        if (has5)
            __builtin_nontemporal_store(tv[4] + Ak[jj[4]] + add * el[4], op + tid + 1024);
    }
}

extern "C" void kernel_launch(void* const* d_in, const int* in_sizes, int n_in,
                              void* d_out, int out_size, void* d_ws, size_t ws_size,
                              hipStream_t stream) {
    (void)in_sizes; (void)n_in; (void)out_size; (void)ws_size;
    const float* features = (const float*)d_in[0];   // (4,512,64)
    const int*   lengths  = (const int*)d_in[1];     // (4,)
    const float* means    = (const float*)d_in[2];   // (32,64)
    const float* cov      = (const float*)d_in[3];   // (64,64)
    const float* plr      = (const float*)d_in[4];   // (32,)
    const float* tlog     = (const float*)d_in[5];   // (32,32)
    const float* ilog     = (const float*)d_in[6];   // (32,)
    float* ws  = (float*)d_ws;
    float* out = (float*)d_out;

    setup_kernel<<<1, 256, 0, stream>>>(cov, means, plr, tlog, ilog, lengths, ws);
    em_kernel<<<512, 256, 0, stream>>>(features, ws);
    csum_kernel<<<132, 64, 0, stream>>>(lengths, ws);
    score_kernel<<<2048, 256, 0, stream>>>(ws, out);
}